// Round 1
// baseline (976.295 us; speedup 1.0000x reference)
//
#include <hip/hip_runtime.h>
#include <hip/hip_bf16.h>
#include <math.h>

// ModelParallelSoftmaxLoss: loss = mean(logsumexp(x@W^T + b) - (x@W^T+b)[lb])
// N=4096, D=512, V=100000.  Fused bf16-MFMA GEMM + max-free sum-exp (logits ~ N(0,0.45^2), safe).

#define N_ROWS 4096
#define DIM    512
#define VOCAB  100000
#define NTILES 782              // ceil(100000/128)
#define VPAD   (NTILES * 128)   // 100096
#define SPLITS 16
#define TPS    49               // ceil(782/16)

typedef __attribute__((ext_vector_type(8))) short bf16x8;
typedef __attribute__((ext_vector_type(4))) float f32x4;

// ---------------- helpers ----------------

__device__ __forceinline__ unsigned short f2bf(float f) {
  // round-to-nearest-even fp32 -> bf16
  unsigned int u = __float_as_uint(f);
  u += 0x7fffu + ((u >> 16) & 1u);
  return (unsigned short)(u >> 16);
}

__device__ __forceinline__ void gload_lds16(const unsigned short* g, unsigned short* l) {
  // async global->LDS, 16B per lane; LDS dest = wave-uniform base + lane*16
  __builtin_amdgcn_global_load_lds(
      (const __attribute__((address_space(1))) unsigned int*)g,
      (__attribute__((address_space(3))) unsigned int*)l, 16, 0, 0);
}

// ---------------- conversion kernels ----------------

__global__ __launch_bounds__(256) void cvt_x_kernel(const float* __restrict__ x,
                                                    unsigned short* __restrict__ xb) {
  int i = (blockIdx.x * 256 + threadIdx.x) * 4;  // grid sized exactly: 2048 blocks
  const float4 f = *(const float4*)(x + i);
  ushort4 o;
  o.x = f2bf(f.x); o.y = f2bf(f.y); o.z = f2bf(f.z); o.w = f2bf(f.w);
  *(ushort4*)(xb + i) = o;
}

__global__ __launch_bounds__(256) void cvt_w_kernel(const float* __restrict__ W,
                                                    unsigned short* __restrict__ wb) {
  long long i = ((long long)blockIdx.x * 256 + threadIdx.x) * 4;  // 50048 blocks: exact
  if (i >= (long long)VPAD * DIM) return;
  if (i < (long long)VOCAB * DIM) {
    const float4 f = *(const float4*)(W + i);
    ushort4 o;
    o.x = f2bf(f.x); o.y = f2bf(f.y); o.z = f2bf(f.z); o.w = f2bf(f.w);
    *(ushort4*)(wb + i) = o;
  } else {
    ushort4 z; z.x = 0; z.y = 0; z.z = 0; z.w = 0;   // pad rows -> 0 (masked in epilogue anyway)
    *(ushort4*)(wb + i) = z;
  }
}

// ---------------- exact fp32 target logit: tgt[r] = x[r] . W[lb[r]] + b[lb[r]] ----------------

__global__ __launch_bounds__(256) void tgt_kernel(const float* __restrict__ x,
                                                  const int* __restrict__ lb,
                                                  const float* __restrict__ W,
                                                  const float* __restrict__ bias,
                                                  float* __restrict__ tgt) {
  const int wv = threadIdx.x >> 6;
  const int lane = threadIdx.x & 63;
  const int row = blockIdx.x * 4 + wv;   // grid 1024 -> 4096 rows exact
  const int t = lb[row];
  const float* xr = x + (size_t)row * DIM;
  const float* wr = W + (size_t)t * DIM;
  float s = 0.f;
#pragma unroll
  for (int i = 0; i < 8; ++i) s += xr[lane + i * 64] * wr[lane + i * 64];
#pragma unroll
  for (int m = 32; m; m >>= 1) s += __shfl_xor(s, m);
  if (lane == 0) tgt[row] = s + bias[t];
}

// ---------------- fused GEMM + sum-exp ----------------
// grid: 512 blocks = 32 m-tiles x 16 V-splits; blockIdx = m*16+s (same-split -> same XCD).
// block: 256 thr = 4 waves; wave w owns rows m0+32w..+31 (2 row-frags x 8 col-frags of 16x16x32).
// Per col-tile: K-loop 16 steps, global_load_lds staging (m97 structure), then epilogue
// accumulates sum(exp(logit+b)) into per-lane running sums per row-slot (max-free).

__global__ __launch_bounds__(256) void lse_kernel(const unsigned short* __restrict__ xb,
                                                  const unsigned short* __restrict__ wb,
                                                  const float* __restrict__ bias,
                                                  float* __restrict__ spart) {
  __shared__ __align__(16) unsigned short ldsA[128 * 32];
  __shared__ __align__(16) unsigned short ldsB[128 * 32];

  const int bI = blockIdx.x;
  const int mtile = bI >> 4;
  const int s = bI & 15;
  const int m0 = mtile * 128;
  const int t0 = s * TPS;
  const int t1 = (t0 + TPS < NTILES) ? (t0 + TPS) : NTILES;

  const int tid  = threadIdx.x;
  const int lane = tid & 63;
  const int wv   = tid >> 6;
  const int srow = lane >> 2;        // staging row-in-chunk 0..15
  const int scol = (lane & 3) * 8;   // staging col 0,8,16,24
  const int fr   = lane & 15;        // frag row (A) / col (B,C)
  const int fq   = lane >> 4;        // frag quad

  float S[2][4];                     // running sum-exp per row-slot
#pragma unroll
  for (int i = 0; i < 2; ++i)
#pragma unroll
    for (int r = 0; r < 4; ++r) S[i][r] = 0.f;

  const unsigned short* gA1 = xb + (size_t)(m0 + wv * 16 + srow) * DIM + scol;
  const unsigned short* gA2 = gA1 + (size_t)64 * DIM;
  unsigned short* lA1 = &ldsA[wv * 512];
  unsigned short* lA2 = &ldsA[(wv + 4) * 512];
  unsigned short* lB1 = &ldsB[wv * 512];
  unsigned short* lB2 = &ldsB[(wv + 4) * 512];

  const f32x4 zero4 = {0.f, 0.f, 0.f, 0.f};

  for (int t = t0; t < t1; ++t) {
    const int v0 = t * 128;
    const unsigned short* gB1 = wb + (size_t)(v0 + wv * 16 + srow) * DIM + scol;
    const unsigned short* gB2 = gB1 + (size_t)64 * DIM;

    f32x4 acc[2][8];
#pragma unroll
    for (int i = 0; i < 2; ++i)
#pragma unroll
      for (int j = 0; j < 8; ++j) acc[i][j] = zero4;

    for (int ks = 0; ks < 16; ++ks) {
      const int k0 = ks * 32;
      gload_lds16(gA1 + k0, lA1);
      gload_lds16(gA2 + k0, lA2);
      gload_lds16(gB1 + k0, lB1);
      gload_lds16(gB2 + k0, lB2);
      __syncthreads();  // drains vmcnt, LDS tiles ready
      bf16x8 a0 = *(const bf16x8*)&ldsA[(32 * wv + fr) * 32 + fq * 8];
      bf16x8 a1 = *(const bf16x8*)&ldsA[(32 * wv + 16 + fr) * 32 + fq * 8];
#pragma unroll
      for (int j = 0; j < 8; ++j) {
        bf16x8 bfj = *(const bf16x8*)&ldsB[(16 * j + fr) * 32 + fq * 8];
        acc[0][j] = __builtin_amdgcn_mfma_f32_16x16x32_bf16(a0, bfj, acc[0][j], 0, 0, 0);
        acc[1][j] = __builtin_amdgcn_mfma_f32_16x16x32_bf16(a1, bfj, acc[1][j], 0, 0, 0);
      }
      __syncthreads();  // LDS reads done before next-step staging overwrites
    }

    // epilogue: logit[row][col] = acc + b[col]; accumulate exp into S.
    // C/D layout: col = v0 + 16*j + fr, row = m0 + 32*wv + 16*i + 4*fq + r.
    float badd[8];
#pragma unroll
    for (int j = 0; j < 8; ++j) {
      const int col = v0 + 16 * j + fr;
      badd[j] = (col < VOCAB) ? bias[col] : -INFINITY;  // exp(-inf)=0 masks tail cols
    }
#pragma unroll
    for (int i = 0; i < 2; ++i)
#pragma unroll
      for (int r = 0; r < 4; ++r) {
        float sum = 0.f;
#pragma unroll
        for (int j = 0; j < 8; ++j) sum += __expf(acc[i][j][r] + badd[j]);
        S[i][r] += sum;
      }
  }

  // reduce over the 16 lanes sharing each row group, write partials
#pragma unroll
  for (int i = 0; i < 2; ++i)
#pragma unroll
    for (int r = 0; r < 4; ++r) {
      float v = S[i][r];
      v += __shfl_xor(v, 1);
      v += __shfl_xor(v, 2);
      v += __shfl_xor(v, 4);
      v += __shfl_xor(v, 8);
      if (fr == 0) {
        const int row = m0 + 32 * wv + 16 * i + 4 * fq + r;
        spart[(size_t)row * SPLITS + s] = v;
      }
    }
}

// ---------------- combine: loss = mean(log(sum_s S_part) - tgt) ----------------

__global__ __launch_bounds__(256) void combine_kernel(const float* __restrict__ spart,
                                                      const float* __restrict__ tgt,
                                                      float* __restrict__ out) {
  __shared__ float red[256];
  float local = 0.f;
  for (int r = threadIdx.x; r < N_ROWS; r += 256) {
    float st = 0.f;
#pragma unroll
    for (int s2 = 0; s2 < SPLITS; ++s2) st += spart[(size_t)r * SPLITS + s2];
    local += __logf(st) - tgt[r];
  }
  red[threadIdx.x] = local;
  __syncthreads();
  for (int step = 128; step; step >>= 1) {
    if (threadIdx.x < step) red[threadIdx.x] += red[threadIdx.x + step];
    __syncthreads();
  }
  if (threadIdx.x == 0) out[0] = red[0] * (1.0f / (float)N_ROWS);
}

// ---------------- launch ----------------
// ws layout: x_bf16 [4096][512] @0 (4 MiB) | W_bf16 [100096][512] (102.3 MiB)
//          | S_part [4096][16] f32 | tgt [4096] f32   -> total ~102 MiB

extern "C" void kernel_launch(void* const* d_in, const int* in_sizes, int n_in,
                              void* d_out, int out_size, void* d_ws, size_t ws_size,
                              hipStream_t stream) {
  const float* x  = (const float*)d_in[0];
  const int*   lb = (const int*)d_in[1];
  const float* W  = (const float*)d_in[2];
  const float* b  = (const float*)d_in[3];
  float* out = (float*)d_out;

  char* ws = (char*)d_ws;
  const size_t OFF_WBF = (size_t)N_ROWS * DIM * 2;                    // 4194304
  const size_t OFF_SP  = OFF_WBF + (size_t)VPAD * DIM * 2;            // +102498304
  const size_t OFF_TGT = OFF_SP + (size_t)N_ROWS * SPLITS * 4;
  unsigned short* xb    = (unsigned short*)(ws);
  unsigned short* wbf   = (unsigned short*)(ws + OFF_WBF);
  float*          spart = (float*)(ws + OFF_SP);
  float*          tgt   = (float*)(ws + OFF_TGT);

  cvt_x_kernel<<<2048, 256, 0, stream>>>(x, xb);
  cvt_w_kernel<<<50048, 256, 0, stream>>>(W, wbf);
  tgt_kernel<<<1024, 256, 0, stream>>>(x, lb, W, b, tgt);
  lse_kernel<<<512, 256, 0, stream>>>(xb, wbf, b, spart);
  combine_kernel<<<1, 256, 0, stream>>>(spart, tgt, out);
}

// Round 2
// 788.432 us; speedup vs baseline: 1.2383x; 1.2383x over previous
//
#include <hip/hip_runtime.h>
#include <hip/hip_bf16.h>
#include <math.h>

// ModelParallelSoftmaxLoss: loss = mean(logsumexp(x@W^T + b) - (x@W^T+b)[lb])
// N=4096, D=512, V=100000.  Fused bf16-MFMA GEMM + max-free sum-exp (logits ~ N(0,0.45^2), safe).
// R2: 32 V-splits (4 blocks/CU) + XOR-swizzled LDS staging (conflict-free frag reads).

#define N_ROWS 4096
#define DIM    512
#define VOCAB  100000
#define NTILES 782              // ceil(100000/128)
#define VPAD   (NTILES * 128)   // 100096
#define SPLITS 32
#define TPS    25               // ceil(782/32)

typedef __attribute__((ext_vector_type(8))) short bf16x8;
typedef __attribute__((ext_vector_type(4))) float f32x4;

// ---------------- helpers ----------------

__device__ __forceinline__ unsigned short f2bf(float f) {
  // round-to-nearest-even fp32 -> bf16
  unsigned int u = __float_as_uint(f);
  u += 0x7fffu + ((u >> 16) & 1u);
  return (unsigned short)(u >> 16);
}

__device__ __forceinline__ void gload_lds16(const unsigned short* g, unsigned short* l) {
  // async global->LDS, 16B per lane; LDS dest = wave-uniform base + lane*16
  __builtin_amdgcn_global_load_lds(
      (const __attribute__((address_space(1))) unsigned int*)g,
      (__attribute__((address_space(3))) unsigned int*)l, 16, 0, 0);
}

// ---------------- conversion kernels ----------------

__global__ __launch_bounds__(256) void cvt_x_kernel(const float* __restrict__ x,
                                                    unsigned short* __restrict__ xb) {
  int i = (blockIdx.x * 256 + threadIdx.x) * 4;  // grid sized exactly: 2048 blocks
  const float4 f = *(const float4*)(x + i);
  ushort4 o;
  o.x = f2bf(f.x); o.y = f2bf(f.y); o.z = f2bf(f.z); o.w = f2bf(f.w);
  *(ushort4*)(xb + i) = o;
}

__global__ __launch_bounds__(256) void cvt_w_kernel(const float* __restrict__ W,
                                                    unsigned short* __restrict__ wb) {
  long long i = ((long long)blockIdx.x * 256 + threadIdx.x) * 4;  // 50048 blocks: exact
  if (i >= (long long)VPAD * DIM) return;
  if (i < (long long)VOCAB * DIM) {
    const float4 f = *(const float4*)(W + i);
    ushort4 o;
    o.x = f2bf(f.x); o.y = f2bf(f.y); o.z = f2bf(f.z); o.w = f2bf(f.w);
    *(ushort4*)(wb + i) = o;
  } else {
    ushort4 z; z.x = 0; z.y = 0; z.z = 0; z.w = 0;   // pad rows -> 0 (masked in epilogue anyway)
    *(ushort4*)(wb + i) = z;
  }
}

// ---------------- exact fp32 target logit: tgt[r] = x[r] . W[lb[r]] + b[lb[r]] ----------------

__global__ __launch_bounds__(256) void tgt_kernel(const float* __restrict__ x,
                                                  const int* __restrict__ lb,
                                                  const float* __restrict__ W,
                                                  const float* __restrict__ bias,
                                                  float* __restrict__ tgt) {
  const int wv = threadIdx.x >> 6;
  const int lane = threadIdx.x & 63;
  const int row = blockIdx.x * 4 + wv;   // grid 1024 -> 4096 rows exact
  const int t = lb[row];
  const float* xr = x + (size_t)row * DIM;
  const float* wr = W + (size_t)t * DIM;
  float s = 0.f;
#pragma unroll
  for (int i = 0; i < 8; ++i) s += xr[lane + i * 64] * wr[lane + i * 64];
#pragma unroll
  for (int m = 32; m; m >>= 1) s += __shfl_xor(s, m);
  if (lane == 0) tgt[row] = s + bias[t];
}

// ---------------- fused GEMM + sum-exp ----------------
// grid: 1024 blocks = 32 m-tiles x 32 V-splits (4 blocks/CU).
// block: 256 thr = 4 waves; wave w owns rows m0+32w..+31 (2 row-frags x 8 col-frags of 16x16x32).
// LDS swizzle: logical 16B chunk (fr,fq) of a 16x32 wave-chunk stored at physical chunk
// fr*4 + (fq ^ ((fr>>1)&3)).  Staging applies the inverse on the GLOBAL col-chunk (lane
// l -> col chunk (l&3)^((l>>3)&3)) since global_load_lds pins LDS dest = lane*16.
// Frag reads then hit all 32 banks exactly 2x per 16-lane phase (structural minimum).

__global__ __launch_bounds__(256, 4) void lse_kernel(const unsigned short* __restrict__ xb,
                                                     const unsigned short* __restrict__ wb,
                                                     const float* __restrict__ bias,
                                                     float* __restrict__ spart) {
  __shared__ __align__(16) unsigned short ldsA[128 * 32];
  __shared__ __align__(16) unsigned short ldsB[128 * 32];

  const int bI = blockIdx.x;
  const int mtile = bI >> 5;
  const int s = bI & 31;
  const int m0 = mtile * 128;
  const int t0 = s * TPS;
  const int t1 = (t0 + TPS < NTILES) ? (t0 + TPS) : NTILES;

  const int tid  = threadIdx.x;
  const int lane = tid & 63;
  const int wv   = tid >> 6;
  const int srow = lane >> 2;                             // staging row-in-chunk 0..15
  const int scol = ((lane & 3) ^ ((lane >> 3) & 3)) * 8;  // swizzled staging col chunk
  const int fr   = lane & 15;                             // frag row (A) / col (B,C)
  const int fq   = lane >> 4;                             // frag quad

  // byte offset of logical (fr,fq) 16B piece within its 1KB row-chunk (swizzled)
  const int roff = ((fr << 2) + (fq ^ ((fr >> 1) & 3))) << 4;
  const char* pA = (const char*)ldsA + wv * 2048;         // chunks 2*wv, 2*wv+1
  const char* pB = (const char*)ldsB;

  float S[2][4];                     // running sum-exp per row-slot
#pragma unroll
  for (int i = 0; i < 2; ++i)
#pragma unroll
    for (int r = 0; r < 4; ++r) S[i][r] = 0.f;

  const unsigned short* gA1 = xb + (size_t)(m0 + wv * 16 + srow) * DIM + scol;
  const unsigned short* gA2 = gA1 + (size_t)64 * DIM;
  unsigned short* lA1 = &ldsA[wv * 512];
  unsigned short* lA2 = &ldsA[(wv + 4) * 512];
  unsigned short* lB1 = &ldsB[wv * 512];
  unsigned short* lB2 = &ldsB[(wv + 4) * 512];

  const f32x4 zero4 = {0.f, 0.f, 0.f, 0.f};

  for (int t = t0; t < t1; ++t) {
    const int v0 = t * 128;
    const unsigned short* gB1 = wb + (size_t)(v0 + wv * 16 + srow) * DIM + scol;
    const unsigned short* gB2 = gB1 + (size_t)64 * DIM;

    f32x4 acc[2][8];
#pragma unroll
    for (int i = 0; i < 2; ++i)
#pragma unroll
      for (int j = 0; j < 8; ++j) acc[i][j] = zero4;

    for (int ks = 0; ks < 16; ++ks) {
      const int k0 = ks * 32;
      gload_lds16(gA1 + k0, lA1);
      gload_lds16(gA2 + k0, lA2);
      gload_lds16(gB1 + k0, lB1);
      gload_lds16(gB2 + k0, lB2);
      __syncthreads();  // drains vmcnt, LDS tiles ready
      bf16x8 a0 = *(const bf16x8*)(pA + roff);
      bf16x8 a1 = *(const bf16x8*)(pA + 1024 + roff);
#pragma unroll
      for (int j = 0; j < 8; ++j) {
        bf16x8 bfj = *(const bf16x8*)(pB + j * 1024 + roff);
        acc[0][j] = __builtin_amdgcn_mfma_f32_16x16x32_bf16(a0, bfj, acc[0][j], 0, 0, 0);
        acc[1][j] = __builtin_amdgcn_mfma_f32_16x16x32_bf16(a1, bfj, acc[1][j], 0, 0, 0);
      }
      __syncthreads();  // LDS reads done before next-step staging overwrites
    }

    // epilogue: logit[row][col] = acc + b[col]; accumulate exp into S.
    // C/D layout: col = v0 + 16*j + fr, row = m0 + 32*wv + 16*i + 4*fq + r.
    float badd[8];
#pragma unroll
    for (int j = 0; j < 8; ++j) {
      const int col = v0 + 16 * j + fr;
      badd[j] = (col < VOCAB) ? bias[col] : -INFINITY;  // exp(-inf)=0 masks tail cols
    }
#pragma unroll
    for (int i = 0; i < 2; ++i)
#pragma unroll
      for (int r = 0; r < 4; ++r) {
        float sum = 0.f;
#pragma unroll
        for (int j = 0; j < 8; ++j) sum += __expf(acc[i][j][r] + badd[j]);
        S[i][r] += sum;
      }
  }

  // reduce over the 16 lanes sharing each row group, write partials
#pragma unroll
  for (int i = 0; i < 2; ++i)
#pragma unroll
    for (int r = 0; r < 4; ++r) {
      float v = S[i][r];
      v += __shfl_xor(v, 1);
      v += __shfl_xor(v, 2);
      v += __shfl_xor(v, 4);
      v += __shfl_xor(v, 8);
      if (fr == 0) {
        const int row = m0 + 32 * wv + 16 * i + 4 * fq + r;
        spart[(size_t)row * SPLITS + s] = v;
      }
    }
}

// ---------------- combine: loss = mean(log(sum_s S_part) - tgt) ----------------

__global__ __launch_bounds__(256) void combine_kernel(const float* __restrict__ spart,
                                                      const float* __restrict__ tgt,
                                                      float* __restrict__ out) {
  __shared__ float red[256];
  float local = 0.f;
  for (int r = threadIdx.x; r < N_ROWS; r += 256) {
    float st = 0.f;
#pragma unroll
    for (int s2 = 0; s2 < SPLITS; ++s2) st += spart[(size_t)r * SPLITS + s2];
    local += __logf(st) - tgt[r];
  }
  red[threadIdx.x] = local;
  __syncthreads();
  for (int step = 128; step; step >>= 1) {
    if (threadIdx.x < step) red[threadIdx.x] += red[threadIdx.x + step];
    __syncthreads();
  }
  if (threadIdx.x == 0) out[0] = red[0] * (1.0f / (float)N_ROWS);
}

// ---------------- launch ----------------
// ws layout: x_bf16 [4096][512] @0 (4 MiB) | W_bf16 [100096][512] (102.3 MiB)
//          | S_part [4096][32] f32 | tgt [4096] f32   -> total ~103 MiB

extern "C" void kernel_launch(void* const* d_in, const int* in_sizes, int n_in,
                              void* d_out, int out_size, void* d_ws, size_t ws_size,
                              hipStream_t stream) {
  const float* x  = (const float*)d_in[0];
  const int*   lb = (const int*)d_in[1];
  const float* W  = (const float*)d_in[2];
  const float* b  = (const float*)d_in[3];
  float* out = (float*)d_out;

  char* ws = (char*)d_ws;
  const size_t OFF_WBF = (size_t)N_ROWS * DIM * 2;                    // 4194304
  const size_t OFF_SP  = OFF_WBF + (size_t)VPAD * DIM * 2;            // +102498304
  const size_t OFF_TGT = OFF_SP + (size_t)N_ROWS * SPLITS * 4;
  unsigned short* xb    = (unsigned short*)(ws);
  unsigned short* wbf   = (unsigned short*)(ws + OFF_WBF);
  float*          spart = (float*)(ws + OFF_SP);
  float*          tgt   = (float*)(ws + OFF_TGT);

  cvt_x_kernel<<<2048, 256, 0, stream>>>(x, xb);
  cvt_w_kernel<<<50048, 256, 0, stream>>>(W, wbf);
  tgt_kernel<<<1024, 256, 0, stream>>>(x, lb, W, b, tgt);
  lse_kernel<<<1024, 256, 0, stream>>>(xb, wbf, b, spart);
  combine_kernel<<<1, 256, 0, stream>>>(spart, tgt, out);
}